// Round 13
// baseline (174.898 us; speedup 1.0000x reference)
//
#include <hip/hip_runtime.h>
#include <hip/hip_bf16.h>

#define BB 4
#define CC 256
#define NN 16384

typedef __hip_bfloat16 bf16;
typedef __attribute__((ext_vector_type(8))) short short8;
typedef __attribute__((ext_vector_type(4))) float f32x4;

__device__ __forceinline__ float b2f(unsigned short u) {
  union { unsigned int i; float f; } x; x.i = ((unsigned int)u) << 16; return x.f;
}
__device__ __forceinline__ short f2bs(float v) {
  bf16 h = __float2bfloat16(v);
  return *reinterpret_cast<short*>(&h);
}
__device__ __forceinline__ f32x4 mfma16(short8 a, short8 b, f32x4 c) {
  return __builtin_amdgcn_mfma_f32_16x16x32_bf16(a, b, c, 0, 0, 0);
}
// async global->LDS, 16B per lane; lds dst is wave-uniform base (HW adds lane*16)
__device__ __forceinline__ void gl_lds16(const bf16* g, const bf16* s) {
  __builtin_amdgcn_global_load_lds(
      (const __attribute__((address_space(1))) unsigned int*)(g),
      (__attribute__((address_space(3))) unsigned int*)(s), 16, 0, 0);
}

// stage x[b, 0..255, n0..n0+127] f32 -> LDS xs[n][j] bf16, XOR-swizzled 16B chunks.
// 512 threads: n = t&127 (lane-coalesced), j-quarter = t>>7; 8 iters x 8 j each.
__device__ __forceinline__ void stage_x_T(const float* __restrict__ xsrc, char* xb_lds, int t) {
  int sn = t & 127;
  int jh = t >> 7;  // 0..3
#pragma unroll
  for (int i = 0; i < 8; ++i) {
    int j0 = (jh + 4 * i) * 8;
    float f[8];
#pragma unroll
    for (int jc = 0; jc < 8; ++jc) f[jc] = xsrc[(size_t)(j0 + jc) * NN + sn];
    short8 pk;
#pragma unroll
    for (int jc = 0; jc < 8; ++jc) pk[jc] = f2bs(f[jc]);
    *(short8*)(xb_lds + sn * 512 + ((j0 * 2) ^ ((sn & 7) << 4))) = pk;
  }
}

// ---------------- prep: reorder/convert weights, BN constants, zero KVD ----------------
__global__ __launch_bounds__(256) void prep_kernel(
    const float* __restrict__ Wqkv, const float* __restrict__ Wproj,
    const float* __restrict__ g, const float* __restrict__ bta,
    const float* __restrict__ mu, const float* __restrict__ var,
    bf16* __restrict__ Wq, bf16* __restrict__ Wkv, bf16* __restrict__ Wp,
    float* __restrict__ bns, float* __restrict__ KVD) {
  int i = blockIdx.x * 256 + threadIdx.x;
  if (i < 1024) KVD[i] = 0.f;
  if (i < 768 * 256) {
    int o = i >> 8, c8 = i & 255;
    int c = o / 3, s = o - 3 * c;
    bf16 bv = __float2bfloat16(Wqkv[i]);
    if (s == 0) Wq[c * 256 + c8] = bv;
    else if (s == 1) Wkv[c * 256 + c8] = bv;
    else Wkv[(256 + c) * 256 + c8] = bv;
  }
  int j = i - 768 * 256;
  if (j >= 0 && j < 256 * 256) Wp[j] = __float2bfloat16(Wproj[j]);
  int k = i - (768 * 256 + 256 * 256);
  if (k >= 0 && k < 256) {
    float sc = g[k] * rsqrtf(var[k] + 1e-5f);
    bns[k] = sc;
    bns[256 + k] = bta[k] - mu[k] * sc;
  }
}

// ---------------- qkv: stage x once; q (clean (n,c) stores), k, v; kvd folded ----------------
__global__ __launch_bounds__(512) void qkv_kernel(
    const float* __restrict__ X, const bf16* __restrict__ Wq, const bf16* __restrict__ Wkv,
    bf16* __restrict__ QT, bf16* __restrict__ KB, bf16* __restrict__ VB,
    float* __restrict__ KVD) {
  __shared__ bf16 xs[128 * 256];  // 64 KB, rows 512B, 16B-chunk ^= (row&7)
  int b = blockIdx.y;
  int n0 = blockIdx.x * 128;
  int t = threadIdx.x, w = t >> 6, l = t & 63, lr = l & 15, lk = l >> 4;
  stage_x_T(X + (size_t)b * CC * NN + n0, (char*)xs, t);
  __syncthreads();
  const char* xb = (const char*)xs;

  // ---- phase q: A=xs (rows n, 8 tiles), B=Wq w*32 c-slice -> QT (n,c); 32B-clean scalar stores ----
  {
    f32x4 acc[8][2] = {};
    for (int k0 = 0; k0 < 256; k0 += 32) {
      short8 a[8];
#pragma unroll
      for (int mt = 0; mt < 8; ++mt) {
        int rn = mt * 16 + lr;
        a[mt] = *(const short8*)(xb + rn * 512 + ((k0 * 2 + lk * 16) ^ ((rn & 7) << 4)));
      }
#pragma unroll
      for (int nt = 0; nt < 2; ++nt) {
        short8 bw = *(const short8*)(Wq + (size_t)(w * 32 + nt * 16 + lr) * CC + k0 + lk * 8);
#pragma unroll
        for (int mt = 0; mt < 8; ++mt) acc[mt][nt] = mfma16(a[mt], bw, acc[mt][nt]);
      }
    }
    bf16* O = QT + ((size_t)b * NN + n0) * CC;
#pragma unroll
    for (int mt = 0; mt < 8; ++mt)
#pragma unroll
      for (int nt = 0; nt < 2; ++nt)
#pragma unroll
        for (int e = 0; e < 4; ++e) {
          int n = mt * 16 + 4 * lk + e;
          int c = w * 32 + nt * 16 + lr;
          float v = acc[mt][nt][e];
          O[(size_t)n * CC + c] = __float2bfloat16(v > 0.f ? v : 0.f);
        }
  }

  // ---- phases k, v: A=Wkv c-slice, B=xs -> (c,n); kvd atomics on k ----
#pragma unroll
  for (int ph = 0; ph < 2; ++ph) {
    f32x4 acc[2][8] = {};
    for (int k0 = 0; k0 < 256; k0 += 32) {
      short8 a[2];
#pragma unroll
      for (int mt = 0; mt < 2; ++mt)
        a[mt] = *(const short8*)(Wkv + (size_t)(ph * 256 + w * 32 + mt * 16 + lr) * CC + k0 + lk * 8);
#pragma unroll
      for (int nt = 0; nt < 8; ++nt) {
        int rn = nt * 16 + lr;
        short8 bb = *(const short8*)(xb + rn * 512 + ((k0 * 2 + lk * 16) ^ ((rn & 7) << 4)));
#pragma unroll
        for (int mt = 0; mt < 2; ++mt) acc[mt][nt] = mfma16(a[mt], bb, acc[mt][nt]);
      }
    }
    bf16* Out = (ph == 0 ? KB : VB) + (size_t)b * CC * NN;
    if (ph == 0) {
#pragma unroll
      for (int mt = 0; mt < 2; ++mt)
#pragma unroll
        for (int e = 0; e < 4; ++e) {
          float s = 0.f;
#pragma unroll
          for (int nt = 0; nt < 8; ++nt) {
            float v = acc[mt][nt][e];
            v = v > 0.f ? v : 0.f;
            acc[mt][nt][e] = v;
            s += v;
          }
          s += __shfl_xor(s, 1);
          s += __shfl_xor(s, 2);
          s += __shfl_xor(s, 4);
          s += __shfl_xor(s, 8);
          int c = w * 32 + mt * 16 + 4 * lk + e;
          if (lr == 0) atomicAdd(&KVD[b * 256 + c], s);
        }
    }
#pragma unroll
    for (int mt = 0; mt < 2; ++mt)
#pragma unroll
      for (int nt = 0; nt < 8; ++nt)
#pragma unroll
        for (int e = 0; e < 4; ++e) {
          int c = w * 32 + mt * 16 + 4 * lk + e;
          int n = nt * 16 + lr;
          Out[(size_t)c * NN + n0 + n] = __float2bfloat16(acc[mt][nt][e]);
        }
  }
}

// ---------------- G2: PART[c][j] partials = k @ v^T, split-K 16 ----------------
__global__ __launch_bounds__(256) void g2_kernel(const bf16* __restrict__ KB,
                                                 const bf16* __restrict__ VB,
                                                 float* __restrict__ PART) {
  int b = blockIdx.z, chunk = blockIdx.y;
  int tc = (blockIdx.x & 1) * 128;
  int tj = (blockIdx.x >> 1) * 128;
  int nb = chunk * 1024;
  int t = threadIdx.x, w = t >> 6, lr = t & 15, lk = (t & 63) >> 4;
  const bf16* A = KB + ((size_t)b * CC + tc + w * 32) * NN + nb;
  const bf16* Bp = VB + ((size_t)b * CC + tj) * NN + nb;
  f32x4 acc[2][8] = {};
  for (int k0 = 0; k0 < 1024; k0 += 32) {
    short8 a[2];
#pragma unroll
    for (int mt = 0; mt < 2; ++mt)
      a[mt] = *(const short8*)(A + (size_t)(mt * 16 + lr) * NN + k0 + lk * 8);
#pragma unroll
    for (int nt = 0; nt < 8; ++nt) {
      short8 bb = *(const short8*)(Bp + (size_t)(nt * 16 + lr) * NN + k0 + lk * 8);
#pragma unroll
      for (int mt = 0; mt < 2; ++mt) acc[mt][nt] = mfma16(a[mt], bb, acc[mt][nt]);
    }
  }
  float* P = PART + (((size_t)(b * 16 + chunk)) << 16);
#pragma unroll
  for (int mt = 0; mt < 2; ++mt)
#pragma unroll
    for (int nt = 0; nt < 8; ++nt)
#pragma unroll
      for (int e = 0; e < 4; ++e) {
        int c = tc + w * 32 + mt * 16 + 4 * lk + e;
        int j = tj + nt * 16 + lr;
        P[(size_t)c * 256 + j] = acc[mt][nt][e];
      }
}

// ---------------- reduce partials -> KVJ bf16 [b][c][j] ----------------
__global__ __launch_bounds__(256) void kvred_kernel(const float* __restrict__ PART, bf16* __restrict__ KVJ) {
  int idx = blockIdx.x * 256 + threadIdx.x;
  int b = idx >> 16, rem = idx & 65535;
  float s = 0.f;
#pragma unroll
  for (int ch = 0; ch < 16; ++ch) s += PART[(((size_t)(b * 16 + ch)) << 16) + rem];
  KVJ[idx] = __float2bfloat16(s);
}

// ---------------- mker: M[o][c] = scale[o] * sum_j Wp[o,j] * KVJ[c,j] ----------------
__global__ __launch_bounds__(256) void mker_kernel(const bf16* __restrict__ Wp,
                                                   const bf16* __restrict__ KVJ,
                                                   const float* __restrict__ bns,
                                                   bf16* __restrict__ Mb) {
  int b = blockIdx.z;
  int o0 = blockIdx.x * 128, c0 = blockIdx.y * 128;
  int t = threadIdx.x, w = t >> 6, lr = t & 15, lk = (t & 63) >> 4;
  const bf16* A = Wp + (size_t)(o0 + w * 32) * 256;
  const bf16* Bp = KVJ + ((size_t)b << 16) + (size_t)c0 * 256;
  f32x4 acc[2][8] = {};
  for (int k0 = 0; k0 < 256; k0 += 32) {
    short8 a[2];
#pragma unroll
    for (int mt = 0; mt < 2; ++mt)
      a[mt] = *(const short8*)(A + (size_t)(mt * 16 + lr) * 256 + k0 + lk * 8);
#pragma unroll
    for (int nt = 0; nt < 8; ++nt) {
      short8 bb = *(const short8*)(Bp + (size_t)(nt * 16 + lr) * 256 + k0 + lk * 8);
#pragma unroll
      for (int mt = 0; mt < 2; ++mt) acc[mt][nt] = mfma16(a[mt], bb, acc[mt][nt]);
    }
  }
#pragma unroll
  for (int mt = 0; mt < 2; ++mt)
#pragma unroll
    for (int nt = 0; nt < 8; ++nt)
#pragma unroll
      for (int e = 0; e < 4; ++e) {
        int o = o0 + w * 32 + mt * 16 + 4 * lk + e;
        int c = c0 + nt * 16 + lr;
        Mb[((size_t)b << 16) + (size_t)o * 256 + c] = __float2bfloat16(acc[mt][nt][e] * bns[o]);
      }
}

// ---------------- g5-lite: gl_lds stage QT, denominator, M-GEMM -> Y ----------------
__global__ __launch_bounds__(512) void g5_kernel(const bf16* __restrict__ QT,
                                                 const bf16* __restrict__ Mb,
                                                 const float* __restrict__ KVD,
                                                 const float* __restrict__ bns,
                                                 float* __restrict__ Y) {
  __shared__ bf16 qs[128 * 256];  // 64 KB, same swizzled layout as qkv's xs
  __shared__ float recip_s[128];
  __shared__ float shift_s[256];
  int b = blockIdx.y;
  int n0 = blockIdx.x * 128;
  int t = threadIdx.x, w = t >> 6, l = t & 63, lr = l & 15, lk = l >> 4;
  if (t < 256) shift_s[t] = bns[256 + t];
  const bf16* qbase = QT + ((size_t)b * NN + n0) * CC;
#pragma unroll
  for (int i = 0; i < 8; ++i) {
    int row2 = w * 16 + i * 2;  // each instr stages rows row2, row2+1
    int ldsOff = row2 * 512 + l * 16;
    int r = ldsOff >> 9;
    int sc = (ldsOff >> 4) & 31;
    int cc = sc ^ (r & 7);
    gl_lds16(qbase + (size_t)r * CC + cc * 8, qs + row2 * 256);
  }
  __syncthreads();
  const char* qb = (const char*)qs;

  // denominator: 4 threads per n-row, 8 chunks each
  {
    int row = t >> 2, qtr = t & 3;
    const float* kd = KVD + b * 256;
    float s = 0.f;
#pragma unroll
    for (int jj = 0; jj < 8; ++jj) {
      int chunk = qtr * 8 + jj;
      short8 v = *(const short8*)(qb + row * 512 + ((chunk * 16) ^ ((row & 7) << 4)));
      const float* kp = kd + chunk * 8;
#pragma unroll
      for (int e = 0; e < 8; ++e) s += b2f((unsigned short)v[e]) * kp[e];
    }
    s += __shfl_xor(s, 1);
    s += __shfl_xor(s, 2);
    if (qtr == 0) recip_s[row] = 1.f / (s + 1e-5f);
  }
  __syncthreads();

  // M-GEMM: A = q (LDS, rows n), B = Mb w*32 o-slice; packed dwordx4 stores along n
  f32x4 acc[8][2] = {};
  for (int k0 = 0; k0 < 256; k0 += 32) {
    short8 a[8];
#pragma unroll
    for (int mt = 0; mt < 8; ++mt) {
      int rn = mt * 16 + lr;
      a[mt] = *(const short8*)(qb + rn * 512 + ((k0 * 2 + lk * 16) ^ ((rn & 7) << 4)));
    }
#pragma unroll
    for (int nt = 0; nt < 2; ++nt) {
      short8 bw = *(const short8*)(Mb + ((size_t)b << 16) + (size_t)(w * 32 + nt * 16 + lr) * 256 + k0 + lk * 8);
#pragma unroll
      for (int mt = 0; mt < 8; ++mt) acc[mt][nt] = mfma16(a[mt], bw, acc[mt][nt]);
    }
  }
  float* Yb = Y + (size_t)b * CC * NN;
#pragma unroll
  for (int mt = 0; mt < 8; ++mt)
#pragma unroll
    for (int nt = 0; nt < 2; ++nt) {
      int o = w * 32 + nt * 16 + lr;
      int nb = mt * 16 + 4 * lk;
      f32x4 out;
#pragma unroll
      for (int e = 0; e < 4; ++e) out[e] = acc[mt][nt][e] * recip_s[nb + e] + shift_s[o];
      *(f32x4*)(Yb + (size_t)o * NN + n0 + nb) = out;
    }
}

extern "C" void kernel_launch(void* const* d_in, const int* in_sizes, int n_in,
                              void* d_out, int out_size, void* d_ws, size_t ws_size,
                              hipStream_t stream) {
  const float* x = (const float*)d_in[0];
  const float* Wqkv = (const float*)d_in[1];
  const float* Wproj = (const float*)d_in[2];
  const float* g = (const float*)d_in[3];
  const float* bta = (const float*)d_in[4];
  const float* mu = (const float*)d_in[5];
  const float* var = (const float*)d_in[6];
  float* Y = (float*)d_out;

  char* ws = (char*)d_ws;
  size_t off = 0;
  auto alloc = [&](size_t bytes) -> void* {
    void* p = ws + off;
    off += (bytes + 255) & ~(size_t)255;
    return p;
  };
  const size_t big = (size_t)BB * NN * CC * 2;  // 33.5 MB
  bf16* QT = (bf16*)alloc(big);
  bf16* KB = (bf16*)alloc(big);
  bf16* VB = (bf16*)alloc(big);
  float* PART = (float*)alloc((size_t)BB * 16 * 65536 * 4);  // 16.8 MB
  bf16* KVJ = (bf16*)alloc((size_t)BB * 65536 * 2);
  bf16* Mbuf = (bf16*)alloc((size_t)BB * 65536 * 2);
  float* KVD = (float*)alloc((size_t)BB * 256 * 4);
  bf16* Wq = (bf16*)alloc(256 * 256 * 2);
  bf16* Wkv = (bf16*)alloc(512 * 256 * 2);
  bf16* Wp = (bf16*)alloc(256 * 256 * 2);
  float* bns = (float*)alloc(512 * 4);

  prep_kernel<<<1025, 256, 0, stream>>>(Wqkv, Wproj, g, bta, mu, var, Wq, Wkv, Wp, bns, KVD);
  qkv_kernel<<<dim3(NN / 128, BB), 512, 0, stream>>>(x, Wq, Wkv, QT, KB, VB, KVD);
  g2_kernel<<<dim3(4, 16, BB), 256, 0, stream>>>(KB, VB, PART);
  kvred_kernel<<<BB * 65536 / 256, 256, 0, stream>>>(PART, KVJ);
  mker_kernel<<<dim3(2, 2, BB), 256, 0, stream>>>(Wp, KVJ, bns, Mbuf);
  g5_kernel<<<dim3(NN / 128, BB), 512, 0, stream>>>(QT, Mbuf, KVD, bns, Y);
}

// Round 14
// 173.471 us; speedup vs baseline: 1.0082x; 1.0082x over previous
//
#include <hip/hip_runtime.h>
#include <hip/hip_bf16.h>

#define BB 4
#define CC 256
#define NN 16384

typedef __hip_bfloat16 bf16;
typedef __attribute__((ext_vector_type(8))) short short8;
typedef __attribute__((ext_vector_type(4))) short s16x4;
typedef __attribute__((ext_vector_type(4))) float f32x4;

__device__ __forceinline__ float b2f(unsigned short u) {
  union { unsigned int i; float f; } x; x.i = ((unsigned int)u) << 16; return x.f;
}
__device__ __forceinline__ short f2bs(float v) {
  bf16 h = __float2bfloat16(v);
  return *reinterpret_cast<short*>(&h);
}
__device__ __forceinline__ f32x4 mfma16(short8 a, short8 b, f32x4 c) {
  return __builtin_amdgcn_mfma_f32_16x16x32_bf16(a, b, c, 0, 0, 0);
}

// stage x[b, 0..255, n0..n0+127] f32 -> LDS xs[n][j] bf16, XOR-swizzled 16B chunks.
// 1024 threads: n = t&127 (lane-coalesced), j-eighth = t>>7; 4 iters x 8 j each.
__device__ __forceinline__ void stage_x_T1024(const float* __restrict__ xsrc, char* xb_lds, int t) {
  int sn = t & 127;
  int jh = t >> 7;  // 0..7
#pragma unroll
  for (int i = 0; i < 4; ++i) {
    int j0 = (jh + 8 * i) * 8;
    float f[8];
#pragma unroll
    for (int jc = 0; jc < 8; ++jc) f[jc] = xsrc[(size_t)(j0 + jc) * NN + sn];
    short8 pk;
#pragma unroll
    for (int jc = 0; jc < 8; ++jc) pk[jc] = f2bs(f[jc]);
    *(short8*)(xb_lds + sn * 512 + ((j0 * 2) ^ ((sn & 7) << 4))) = pk;
  }
}

// ---------------- prep: reorder/convert weights, BN constants, zero KVD ----------------
__global__ __launch_bounds__(256) void prep_kernel(
    const float* __restrict__ Wqkv, const float* __restrict__ Wproj,
    const float* __restrict__ g, const float* __restrict__ bta,
    const float* __restrict__ mu, const float* __restrict__ var,
    bf16* __restrict__ Wq, bf16* __restrict__ Wkv, bf16* __restrict__ Wp,
    float* __restrict__ bns, float* __restrict__ KVD) {
  int i = blockIdx.x * 256 + threadIdx.x;
  if (i < 1024) KVD[i] = 0.f;
  if (i < 768 * 256) {
    int o = i >> 8, c8 = i & 255;
    int c = o / 3, s = o - 3 * c;
    bf16 bv = __float2bfloat16(Wqkv[i]);
    if (s == 0) Wq[c * 256 + c8] = bv;
    else if (s == 1) Wkv[c * 256 + c8] = bv;
    else Wkv[(256 + c) * 256 + c8] = bv;
  }
  int j = i - 768 * 256;
  if (j >= 0 && j < 256 * 256) Wp[j] = __float2bfloat16(Wproj[j]);
  int k = i - (768 * 256 + 256 * 256);
  if (k >= 0 && k < 256) {
    float sc = g[k] * rsqrtf(var[k] + 1e-5f);
    bns[k] = sc;
    bns[256 + k] = bta[k] - mu[k] * sc;
  }
}

// ---------------- kv: 1024 thr; waves 0-7 compute k, waves 8-15 compute v (one phase) ----------------
__global__ __launch_bounds__(1024) void kv_kernel(
    const float* __restrict__ X, const bf16* __restrict__ Wkv,
    bf16* __restrict__ KB, bf16* __restrict__ VB, float* __restrict__ KVD) {
  __shared__ bf16 xs[128 * 256];  // 64 KB, rows 512B, 16B-chunk ^= (row&7)
  int b = blockIdx.y;
  int n0 = blockIdx.x * 128;
  int t = threadIdx.x, w = t >> 6, l = t & 63, lr = l & 15, lk = l >> 4;
  int isV = w >> 3, ws = w & 7;
  stage_x_T1024(X + (size_t)b * CC * NN + n0, (char*)xs, t);
  __syncthreads();
  const char* xb = (const char*)xs;

  f32x4 acc[2][8] = {};
  for (int k0 = 0; k0 < 256; k0 += 32) {
    short8 a[2];
#pragma unroll
    for (int mt = 0; mt < 2; ++mt)
      a[mt] = *(const short8*)(Wkv + (size_t)(isV * 256 + ws * 32 + mt * 16 + lr) * CC + k0 + lk * 8);
#pragma unroll
    for (int nt = 0; nt < 8; ++nt) {
      int rn = nt * 16 + lr;
      short8 bb = *(const short8*)(xb + rn * 512 + ((k0 * 2 + lk * 16) ^ ((rn & 7) << 4)));
#pragma unroll
      for (int mt = 0; mt < 2; ++mt) acc[mt][nt] = mfma16(a[mt], bb, acc[mt][nt]);
    }
  }
  bf16* Out = (isV ? VB : KB) + (size_t)b * CC * NN;
  if (!isV) {
    // relu + kvd column sums (lanes sharing c: lr varies over n)
#pragma unroll
    for (int mt = 0; mt < 2; ++mt)
#pragma unroll
      for (int e = 0; e < 4; ++e) {
        float s = 0.f;
#pragma unroll
        for (int nt = 0; nt < 8; ++nt) {
          float v = acc[mt][nt][e];
          v = v > 0.f ? v : 0.f;
          acc[mt][nt][e] = v;
          s += v;
        }
        s += __shfl_xor(s, 1);
        s += __shfl_xor(s, 2);
        s += __shfl_xor(s, 4);
        s += __shfl_xor(s, 8);
        int c = ws * 32 + mt * 16 + 4 * lk + e;
        if (lr == 0) atomicAdd(&KVD[b * 256 + c], s);
      }
  }
#pragma unroll
  for (int mt = 0; mt < 2; ++mt)
#pragma unroll
    for (int nt = 0; nt < 8; ++nt)
#pragma unroll
      for (int e = 0; e < 4; ++e) {
        int c = ws * 32 + mt * 16 + 4 * lk + e;
        int n = nt * 16 + lr;
        Out[(size_t)c * NN + n0 + n] = __float2bfloat16(acc[mt][nt][e]);
      }
}

// ---------------- G2: PART[c][j] partials = k @ v^T, split-K 16 ----------------
__global__ __launch_bounds__(256) void g2_kernel(const bf16* __restrict__ KB,
                                                 const bf16* __restrict__ VB,
                                                 float* __restrict__ PART) {
  int b = blockIdx.z, chunk = blockIdx.y;
  int tc = (blockIdx.x & 1) * 128;
  int tj = (blockIdx.x >> 1) * 128;
  int nb = chunk * 1024;
  int t = threadIdx.x, w = t >> 6, lr = t & 15, lk = (t & 63) >> 4;
  const bf16* A = KB + ((size_t)b * CC + tc + w * 32) * NN + nb;
  const bf16* Bp = VB + ((size_t)b * CC + tj) * NN + nb;
  f32x4 acc[2][8] = {};
  for (int k0 = 0; k0 < 1024; k0 += 32) {
    short8 a[2];
#pragma unroll
    for (int mt = 0; mt < 2; ++mt)
      a[mt] = *(const short8*)(A + (size_t)(mt * 16 + lr) * NN + k0 + lk * 8);
#pragma unroll
    for (int nt = 0; nt < 8; ++nt) {
      short8 bb = *(const short8*)(Bp + (size_t)(nt * 16 + lr) * NN + k0 + lk * 8);
#pragma unroll
      for (int mt = 0; mt < 2; ++mt) acc[mt][nt] = mfma16(a[mt], bb, acc[mt][nt]);
    }
  }
  float* P = PART + (((size_t)(b * 16 + chunk)) << 16);
#pragma unroll
  for (int mt = 0; mt < 2; ++mt)
#pragma unroll
    for (int nt = 0; nt < 8; ++nt)
#pragma unroll
      for (int e = 0; e < 4; ++e) {
        int c = tc + w * 32 + mt * 16 + 4 * lk + e;
        int j = tj + nt * 16 + lr;
        P[(size_t)c * 256 + j] = acc[mt][nt][e];
      }
}

// ---------------- reduce partials -> KVJ bf16 [b][c][j] ----------------
__global__ __launch_bounds__(256) void kvred_kernel(const float* __restrict__ PART, bf16* __restrict__ KVJ) {
  int idx = blockIdx.x * 256 + threadIdx.x;
  int b = idx >> 16, rem = idx & 65535;
  float s = 0.f;
#pragma unroll
  for (int ch = 0; ch < 16; ++ch) s += PART[(((size_t)(b * 16 + ch)) << 16) + rem];
  KVJ[idx] = __float2bfloat16(s);
}

// ---------------- mker: M[o][c] = scale[o] * sum_j Wp[o,j] * KVJ[c,j] ----------------
__global__ __launch_bounds__(256) void mker_kernel(const bf16* __restrict__ Wp,
                                                   const bf16* __restrict__ KVJ,
                                                   const float* __restrict__ bns,
                                                   bf16* __restrict__ Mb) {
  int b = blockIdx.z;
  int o0 = blockIdx.x * 128, c0 = blockIdx.y * 128;
  int t = threadIdx.x, w = t >> 6, lr = t & 15, lk = (t & 63) >> 4;
  const bf16* A = Wp + (size_t)(o0 + w * 32) * 256;
  const bf16* Bp = KVJ + ((size_t)b << 16) + (size_t)c0 * 256;
  f32x4 acc[2][8] = {};
  for (int k0 = 0; k0 < 256; k0 += 32) {
    short8 a[2];
#pragma unroll
    for (int mt = 0; mt < 2; ++mt)
      a[mt] = *(const short8*)(A + (size_t)(mt * 16 + lr) * 256 + k0 + lk * 8);
#pragma unroll
    for (int nt = 0; nt < 8; ++nt) {
      short8 bb = *(const short8*)(Bp + (size_t)(nt * 16 + lr) * 256 + k0 + lk * 8);
#pragma unroll
      for (int mt = 0; mt < 2; ++mt) acc[mt][nt] = mfma16(a[mt], bb, acc[mt][nt]);
    }
  }
#pragma unroll
  for (int mt = 0; mt < 2; ++mt)
#pragma unroll
    for (int nt = 0; nt < 8; ++nt)
#pragma unroll
      for (int e = 0; e < 4; ++e) {
        int o = o0 + w * 32 + mt * 16 + 4 * lk + e;
        int c = c0 + nt * 16 + lr;
        Mb[((size_t)b << 16) + (size_t)o * 256 + c] = __float2bfloat16(acc[mt][nt][e] * bns[o]);
      }
}

// ---------------- g5: 1024 thr; stage x, q (16 waves x 16c), den, M-GEMM (16 waves x 16o) ----------------
__global__ __launch_bounds__(1024) void g5_kernel(const float* __restrict__ X,
                                                  const bf16* __restrict__ Wq,
                                                  const bf16* __restrict__ Mb,
                                                  const float* __restrict__ KVD,
                                                  const float* __restrict__ bns,
                                                  float* __restrict__ Y) {
  __shared__ bf16 qs[128 * 256];  // 64 KB: x tile, then q tile
  __shared__ float recip_s[128];
  __shared__ float shift_s[256];
  int b = blockIdx.y;
  int n0 = blockIdx.x * 128;
  int t = threadIdx.x, w = t >> 6, l = t & 63, lr = l & 15, lk = l >> 4;
  if (t < 256) shift_s[t] = bns[256 + t];
  stage_x_T1024(X + (size_t)b * CC * NN + n0, (char*)qs, t);
  __syncthreads();
  char* qb = (char*)qs;

  // ---- q phase: A=Wq 16-c slice (rows via lr), B=xs n-tiles; acc[8] = 16c x 128n ----
  {
    f32x4 qa[8] = {};
    for (int k0 = 0; k0 < 256; k0 += 32) {
      short8 a = *(const short8*)(Wq + (size_t)(w * 16 + lr) * CC + k0 + lk * 8);
#pragma unroll
      for (int nt = 0; nt < 8; ++nt) {
        int rn = nt * 16 + lr;
        short8 bb = *(const short8*)(qb + rn * 512 + ((k0 * 2 + lk * 16) ^ ((rn & 7) << 4)));
        qa[nt] = mfma16(a, bb, qa[nt]);
      }
    }
    __syncthreads();  // all waves done reading x tile
    // writeback relu(q): c = w*16 + 4*lk + e (4 consecutive c -> b64), n = nt*16 + lr
#pragma unroll
    for (int nt = 0; nt < 8; ++nt) {
      int n = nt * 16 + lr;
      int c0 = w * 16 + 4 * lk;
      s16x4 pk;
#pragma unroll
      for (int e = 0; e < 4; ++e) {
        float v = qa[nt][e];
        pk[e] = f2bs(v > 0.f ? v : 0.f);
      }
      *(s16x4*)(qb + n * 512 + ((c0 * 2) ^ ((n & 7) << 4))) = pk;
    }
  }
  __syncthreads();

  // ---- denominator: 8 threads per n-row, 4 chunks each ----
  {
    int row = t >> 3, oct = t & 7;
    const float* kd = KVD + b * 256;
    float s = 0.f;
#pragma unroll
    for (int jj = 0; jj < 4; ++jj) {
      int chunk = oct * 4 + jj;
      short8 v = *(const short8*)(qb + row * 512 + ((chunk * 16) ^ ((row & 7) << 4)));
      const float* kp = kd + chunk * 8;
#pragma unroll
      for (int e = 0; e < 8; ++e) s += b2f((unsigned short)v[e]) * kp[e];
    }
    s += __shfl_xor(s, 1);
    s += __shfl_xor(s, 2);
    s += __shfl_xor(s, 4);
    if (oct == 0) recip_s[row] = 1.f / (s + 1e-5f);
  }
  __syncthreads();

  // ---- M-GEMM: A = q (LDS, 8 n-tiles), B = Mb 16-o slice; f32x4 stores along n ----
  f32x4 acc[8] = {};
  for (int k0 = 0; k0 < 256; k0 += 32) {
    short8 bw = *(const short8*)(Mb + ((size_t)b << 16) + (size_t)(w * 16 + lr) * 256 + k0 + lk * 8);
#pragma unroll
    for (int mt = 0; mt < 8; ++mt) {
      int rn = mt * 16 + lr;
      short8 a = *(const short8*)(qb + rn * 512 + ((k0 * 2 + lk * 16) ^ ((rn & 7) << 4)));
      acc[mt] = mfma16(a, bw, acc[mt]);
    }
  }
  float* Yb = Y + (size_t)b * CC * NN;
#pragma unroll
  for (int mt = 0; mt < 8; ++mt) {
    int o = w * 16 + lr;
    int nb = mt * 16 + 4 * lk;
    f32x4 out;
#pragma unroll
    for (int e = 0; e < 4; ++e) out[e] = acc[mt][e] * recip_s[nb + e] + shift_s[o];
    *(f32x4*)(Yb + (size_t)o * NN + n0 + nb) = out;
  }
}

extern "C" void kernel_launch(void* const* d_in, const int* in_sizes, int n_in,
                              void* d_out, int out_size, void* d_ws, size_t ws_size,
                              hipStream_t stream) {
  const float* x = (const float*)d_in[0];
  const float* Wqkv = (const float*)d_in[1];
  const float* Wproj = (const float*)d_in[2];
  const float* g = (const float*)d_in[3];
  const float* bta = (const float*)d_in[4];
  const float* mu = (const float*)d_in[5];
  const float* var = (const float*)d_in[6];
  float* Y = (float*)d_out;

  char* ws = (char*)d_ws;
  size_t off = 0;
  auto alloc = [&](size_t bytes) -> void* {
    void* p = ws + off;
    off += (bytes + 255) & ~(size_t)255;
    return p;
  };
  const size_t big = (size_t)BB * NN * CC * 2;  // 33.5 MB
  bf16* KB = (bf16*)alloc(big);
  bf16* VB = (bf16*)alloc(big);
  float* PART = (float*)alloc((size_t)BB * 16 * 65536 * 4);  // 16.8 MB
  bf16* KVJ = (bf16*)alloc((size_t)BB * 65536 * 2);
  bf16* Mbuf = (bf16*)alloc((size_t)BB * 65536 * 2);
  float* KVD = (float*)alloc((size_t)BB * 256 * 4);
  bf16* Wq = (bf16*)alloc(256 * 256 * 2);
  bf16* Wkv = (bf16*)alloc(512 * 256 * 2);
  bf16* Wp = (bf16*)alloc(256 * 256 * 2);
  float* bns = (float*)alloc(512 * 4);

  prep_kernel<<<1025, 256, 0, stream>>>(Wqkv, Wproj, g, bta, mu, var, Wq, Wkv, Wp, bns, KVD);
  kv_kernel<<<dim3(NN / 128, BB), 1024, 0, stream>>>(x, Wkv, KB, VB, KVD);
  g2_kernel<<<dim3(4, 16, BB), 256, 0, stream>>>(KB, VB, PART);
  kvred_kernel<<<BB * 65536 / 256, 256, 0, stream>>>(PART, KVJ);
  mker_kernel<<<dim3(2, 2, BB), 256, 0, stream>>>(Wp, KVJ, bns, Mbuf);
  g5_kernel<<<dim3(NN / 128, BB), 1024, 0, stream>>>(x, Wq, Mbuf, KVD, bns, Y);
}

// Round 15
// 166.285 us; speedup vs baseline: 1.0518x; 1.0432x over previous
//
#include <hip/hip_runtime.h>
#include <hip/hip_bf16.h>

#define BB 4
#define CC 256
#define NN 16384

typedef __hip_bfloat16 bf16;
typedef __attribute__((ext_vector_type(8))) short short8;
typedef __attribute__((ext_vector_type(4))) short s16x4;
typedef __attribute__((ext_vector_type(4))) float f32x4;

__device__ __forceinline__ float b2f(unsigned short u) {
  union { unsigned int i; float f; } x; x.i = ((unsigned int)u) << 16; return x.f;
}
__device__ __forceinline__ short f2bs(float v) {
  bf16 h = __float2bfloat16(v);
  return *reinterpret_cast<short*>(&h);
}
__device__ __forceinline__ f32x4 mfma16(short8 a, short8 b, f32x4 c) {
  return __builtin_amdgcn_mfma_f32_16x16x32_bf16(a, b, c, 0, 0, 0);
}

// stage x[b, 0..255, n0..n0+127] f32 -> LDS xs[n][j] bf16, XOR-swizzled 16B chunks.
// 512 threads: n = t&127 (lane-coalesced), j-quarter = t>>7; 8 iters x 8 j each.
__device__ __forceinline__ void stage_x_T(const float* __restrict__ xsrc, char* xb_lds, int t) {
  int sn = t & 127;
  int jh = t >> 7;  // 0..3
#pragma unroll
  for (int i = 0; i < 8; ++i) {
    int j0 = (jh + 4 * i) * 8;
    float f[8];
#pragma unroll
    for (int jc = 0; jc < 8; ++jc) f[jc] = xsrc[(size_t)(j0 + jc) * NN + sn];
    short8 pk;
#pragma unroll
    for (int jc = 0; jc < 8; ++jc) pk[jc] = f2bs(f[jc]);
    *(short8*)(xb_lds + sn * 512 + ((j0 * 2) ^ ((sn & 7) << 4))) = pk;
  }
}

// ---------------- prep: reorder/convert weights, BN constants, zero KVD ----------------
__global__ __launch_bounds__(256) void prep_kernel(
    const float* __restrict__ Wqkv, const float* __restrict__ Wproj,
    const float* __restrict__ g, const float* __restrict__ bta,
    const float* __restrict__ mu, const float* __restrict__ var,
    bf16* __restrict__ Wq, bf16* __restrict__ Wkv, bf16* __restrict__ Wp,
    float* __restrict__ bns, float* __restrict__ KVD) {
  int i = blockIdx.x * 256 + threadIdx.x;
  if (i < 1024) KVD[i] = 0.f;
  if (i < 768 * 256) {
    int o = i >> 8, c8 = i & 255;
    int c = o / 3, s = o - 3 * c;
    bf16 bv = __float2bfloat16(Wqkv[i]);
    if (s == 0) Wq[c * 256 + c8] = bv;
    else if (s == 1) Wkv[c * 256 + c8] = bv;
    else Wkv[(256 + c) * 256 + c8] = bv;
  }
  int j = i - 768 * 256;
  if (j >= 0 && j < 256 * 256) Wp[j] = __float2bfloat16(Wproj[j]);
  int k = i - (768 * 256 + 256 * 256);
  if (k >= 0 && k < 256) {
    float sc = g[k] * rsqrtf(var[k] + 1e-5f);
    bns[k] = sc;
    bns[256 + k] = bta[k] - mu[k] * sc;
  }
}

// ---------------- kv: stage x; k phase (preloaded frags) + v phase; kvd folded ----------------
__global__ __launch_bounds__(512, 2) void kv_kernel(
    const float* __restrict__ X, const bf16* __restrict__ Wkv,
    bf16* __restrict__ KB, bf16* __restrict__ VB, float* __restrict__ KVD) {
  __shared__ bf16 xs[128 * 256];  // 64 KB, rows 512B, 16B-chunk ^= (row&7)
  int b = blockIdx.y;
  int n0 = blockIdx.x * 128;
  int t = threadIdx.x, w = t >> 6, l = t & 63, lr = l & 15, lk = l >> 4;
  // preload k-phase weight frags for first 4 K-steps (latency hides under staging)
  short8 wk[4][2];
#pragma unroll
  for (int k0i = 0; k0i < 4; ++k0i)
#pragma unroll
    for (int mt = 0; mt < 2; ++mt)
      wk[k0i][mt] = *(const short8*)(Wkv + (size_t)(w * 32 + mt * 16 + lr) * CC + k0i * 32 + lk * 8);
  stage_x_T(X + (size_t)b * CC * NN + n0, (char*)xs, t);
  __syncthreads();
  const char* xb = (const char*)xs;

  // ---- phase k: A=Wkv c-slice, B=xs -> (c,n); kvd atomics ----
  {
    f32x4 acc[2][8] = {};
#pragma unroll
    for (int k0i = 0; k0i < 8; ++k0i) {
      short8 a[2];
#pragma unroll
      for (int mt = 0; mt < 2; ++mt)
        a[mt] = (k0i < 4) ? wk[k0i][mt]
                          : *(const short8*)(Wkv + (size_t)(w * 32 + mt * 16 + lr) * CC + k0i * 32 + lk * 8);
#pragma unroll
      for (int nt = 0; nt < 8; ++nt) {
        int rn = nt * 16 + lr;
        short8 bb = *(const short8*)(xb + rn * 512 + ((k0i * 64 + lk * 16) ^ ((rn & 7) << 4)));
#pragma unroll
        for (int mt = 0; mt < 2; ++mt) acc[mt][nt] = mfma16(a[mt], bb, acc[mt][nt]);
      }
    }
    bf16* Out = KB + (size_t)b * CC * NN;
#pragma unroll
    for (int mt = 0; mt < 2; ++mt)
#pragma unroll
      for (int e = 0; e < 4; ++e) {
        float s = 0.f;
#pragma unroll
        for (int nt = 0; nt < 8; ++nt) {
          float v = acc[mt][nt][e];
          v = v > 0.f ? v : 0.f;
          acc[mt][nt][e] = v;
          s += v;
        }
        s += __shfl_xor(s, 1);
        s += __shfl_xor(s, 2);
        s += __shfl_xor(s, 4);
        s += __shfl_xor(s, 8);
        int c = w * 32 + mt * 16 + 4 * lk + e;
        if (lr == 0) atomicAdd(&KVD[b * 256 + c], s);
      }
#pragma unroll
    for (int mt = 0; mt < 2; ++mt)
#pragma unroll
      for (int nt = 0; nt < 8; ++nt)
#pragma unroll
        for (int e = 0; e < 4; ++e) {
          int c = w * 32 + mt * 16 + 4 * lk + e;
          int n = nt * 16 + lr;
          Out[(size_t)c * NN + n0 + n] = __float2bfloat16(acc[mt][nt][e]);
        }
  }
  // ---- phase v (weights L2-warm, inline loads) ----
  {
    f32x4 acc[2][8] = {};
    for (int k0 = 0; k0 < 256; k0 += 32) {
      short8 a[2];
#pragma unroll
      for (int mt = 0; mt < 2; ++mt)
        a[mt] = *(const short8*)(Wkv + (size_t)(256 + w * 32 + mt * 16 + lr) * CC + k0 + lk * 8);
#pragma unroll
      for (int nt = 0; nt < 8; ++nt) {
        int rn = nt * 16 + lr;
        short8 bb = *(const short8*)(xb + rn * 512 + ((k0 * 2 + lk * 16) ^ ((rn & 7) << 4)));
#pragma unroll
        for (int mt = 0; mt < 2; ++mt) acc[mt][nt] = mfma16(a[mt], bb, acc[mt][nt]);
      }
    }
    bf16* Out = VB + (size_t)b * CC * NN;
#pragma unroll
    for (int mt = 0; mt < 2; ++mt)
#pragma unroll
      for (int nt = 0; nt < 8; ++nt)
#pragma unroll
        for (int e = 0; e < 4; ++e) {
          int c = w * 32 + mt * 16 + 4 * lk + e;
          int n = nt * 16 + lr;
          Out[(size_t)c * NN + n0 + n] = __float2bfloat16(acc[mt][nt][e]);
        }
  }
}

// ---------------- G2: PART[c][j] partials = k @ v^T, split-K 16 ----------------
__global__ __launch_bounds__(256) void g2_kernel(const bf16* __restrict__ KB,
                                                 const bf16* __restrict__ VB,
                                                 float* __restrict__ PART) {
  int b = blockIdx.z, chunk = blockIdx.y;
  int tc = (blockIdx.x & 1) * 128;
  int tj = (blockIdx.x >> 1) * 128;
  int nb = chunk * 1024;
  int t = threadIdx.x, w = t >> 6, lr = t & 15, lk = (t & 63) >> 4;
  const bf16* A = KB + ((size_t)b * CC + tc + w * 32) * NN + nb;
  const bf16* Bp = VB + ((size_t)b * CC + tj) * NN + nb;
  f32x4 acc[2][8] = {};
  for (int k0 = 0; k0 < 1024; k0 += 32) {
    short8 a[2];
#pragma unroll
    for (int mt = 0; mt < 2; ++mt)
      a[mt] = *(const short8*)(A + (size_t)(mt * 16 + lr) * NN + k0 + lk * 8);
#pragma unroll
    for (int nt = 0; nt < 8; ++nt) {
      short8 bb = *(const short8*)(Bp + (size_t)(nt * 16 + lr) * NN + k0 + lk * 8);
#pragma unroll
      for (int mt = 0; mt < 2; ++mt) acc[mt][nt] = mfma16(a[mt], bb, acc[mt][nt]);
    }
  }
  float* P = PART + (((size_t)(b * 16 + chunk)) << 16);
#pragma unroll
  for (int mt = 0; mt < 2; ++mt)
#pragma unroll
    for (int nt = 0; nt < 8; ++nt)
#pragma unroll
      for (int e = 0; e < 4; ++e) {
        int c = tc + w * 32 + mt * 16 + 4 * lk + e;
        int j = tj + nt * 16 + lr;
        P[(size_t)c * 256 + j] = acc[mt][nt][e];
      }
}

// ---------------- reduce partials -> KVJ bf16 [b][c][j] ----------------
__global__ __launch_bounds__(256) void kvred_kernel(const float* __restrict__ PART, bf16* __restrict__ KVJ) {
  int idx = blockIdx.x * 256 + threadIdx.x;
  int b = idx >> 16, rem = idx & 65535;
  float s = 0.f;
#pragma unroll
  for (int ch = 0; ch < 16; ++ch) s += PART[(((size_t)(b * 16 + ch)) << 16) + rem];
  KVJ[idx] = __float2bfloat16(s);
}

// ---------------- mker: M[o][c] = scale[o] * sum_j Wp[o,j] * KVJ[c,j] ----------------
__global__ __launch_bounds__(256) void mker_kernel(const bf16* __restrict__ Wp,
                                                   const bf16* __restrict__ KVJ,
                                                   const float* __restrict__ bns,
                                                   bf16* __restrict__ Mb) {
  int b = blockIdx.z;
  int o0 = blockIdx.x * 128, c0 = blockIdx.y * 128;
  int t = threadIdx.x, w = t >> 6, lr = t & 15, lk = (t & 63) >> 4;
  const bf16* A = Wp + (size_t)(o0 + w * 32) * 256;
  const bf16* Bp = KVJ + ((size_t)b << 16) + (size_t)c0 * 256;
  f32x4 acc[2][8] = {};
  for (int k0 = 0; k0 < 256; k0 += 32) {
    short8 a[2];
#pragma unroll
    for (int mt = 0; mt < 2; ++mt)
      a[mt] = *(const short8*)(A + (size_t)(mt * 16 + lr) * 256 + k0 + lk * 8);
#pragma unroll
    for (int nt = 0; nt < 8; ++nt) {
      short8 bb = *(const short8*)(Bp + (size_t)(nt * 16 + lr) * 256 + k0 + lk * 8);
#pragma unroll
      for (int mt = 0; mt < 2; ++mt) acc[mt][nt] = mfma16(a[mt], bb, acc[mt][nt]);
    }
  }
#pragma unroll
  for (int mt = 0; mt < 2; ++mt)
#pragma unroll
    for (int nt = 0; nt < 8; ++nt)
#pragma unroll
      for (int e = 0; e < 4; ++e) {
        int o = o0 + w * 32 + mt * 16 + 4 * lk + e;
        int c = c0 + nt * 16 + lr;
        Mb[((size_t)b << 16) + (size_t)o * 256 + c] = __float2bfloat16(acc[mt][nt][e] * bns[o]);
      }
}

// ---------------- g5: stage x, q (preloaded frags) -> LDS, den, M-GEMM ----------------
__global__ __launch_bounds__(512, 2) void g5_kernel(const float* __restrict__ X,
                                                    const bf16* __restrict__ Wq,
                                                    const bf16* __restrict__ Mb,
                                                    const float* __restrict__ KVD,
                                                    const float* __restrict__ bns,
                                                    float* __restrict__ Y) {
  __shared__ bf16 qs[128 * 256];  // 64 KB: x tile, then q tile
  __shared__ float recip_s[128];
  __shared__ float shift_s[256];
  int b = blockIdx.y;
  int n0 = blockIdx.x * 128;
  int t = threadIdx.x, w = t >> 6, l = t & 63, lr = l & 15, lk = l >> 4;
  if (t < 256) shift_s[t] = bns[256 + t];
  // preload q-phase weight frags for first 4 K-steps
  short8 wq[4][2];
#pragma unroll
  for (int k0i = 0; k0i < 4; ++k0i)
#pragma unroll
    for (int mt = 0; mt < 2; ++mt)
      wq[k0i][mt] = *(const short8*)(Wq + (size_t)(w * 32 + mt * 16 + lr) * CC + k0i * 32 + lk * 8);
  stage_x_T(X + (size_t)b * CC * NN + n0, (char*)qs, t);
  __syncthreads();
  char* qb = (char*)qs;

  // ---- q phase: A=Wq 32-c slice, B=xs; writeback relu(q) into qs ----
  {
    f32x4 qa[2][8] = {};
#pragma unroll
    for (int k0i = 0; k0i < 8; ++k0i) {
      short8 a[2];
#pragma unroll
      for (int mt = 0; mt < 2; ++mt)
        a[mt] = (k0i < 4) ? wq[k0i][mt]
                          : *(const short8*)(Wq + (size_t)(w * 32 + mt * 16 + lr) * CC + k0i * 32 + lk * 8);
#pragma unroll
      for (int nt = 0; nt < 8; ++nt) {
        int rn = nt * 16 + lr;
        short8 bb = *(const short8*)(qb + rn * 512 + ((k0i * 64 + lk * 16) ^ ((rn & 7) << 4)));
#pragma unroll
        for (int mt = 0; mt < 2; ++mt) qa[mt][nt] = mfma16(a[mt], bb, qa[mt][nt]);
      }
    }
    __syncthreads();  // all waves done reading the x tile
#pragma unroll
    for (int mt = 0; mt < 2; ++mt)
#pragma unroll
      for (int nt = 0; nt < 8; ++nt) {
        int n = nt * 16 + lr;
        int c0 = w * 32 + mt * 16 + 4 * lk;
        s16x4 pk;
#pragma unroll
        for (int e = 0; e < 4; ++e) {
          float v = qa[mt][nt][e];
          pk[e] = f2bs(v > 0.f ? v : 0.f);
        }
        *(s16x4*)(qb + n * 512 + ((c0 * 2) ^ ((n & 7) << 4))) = pk;
      }
  }
  __syncthreads();

  // ---- denominator: 4 threads per n-row, 8 chunks each ----
  {
    int row = t >> 2, qtr = t & 3;
    const float* kd = KVD + b * 256;
    float s = 0.f;
#pragma unroll
    for (int jj = 0; jj < 8; ++jj) {
      int chunk = qtr * 8 + jj;
      short8 v = *(const short8*)(qb + row * 512 + ((chunk * 16) ^ ((row & 7) << 4)));
      const float* kp = kd + chunk * 8;
#pragma unroll
      for (int e = 0; e < 8; ++e) s += b2f((unsigned short)v[e]) * kp[e];
    }
    s += __shfl_xor(s, 1);
    s += __shfl_xor(s, 2);
    if (qtr == 0) recip_s[row] = 1.f / (s + 1e-5f);
  }
  __syncthreads();

  // ---- M-GEMM: A = q (LDS, rows n), B = Mb w*32 o-slice; packed dwordx4 stores along n ----
  f32x4 acc[8][2] = {};
  for (int k0 = 0; k0 < 256; k0 += 32) {
    short8 a[8];
#pragma unroll
    for (int mt = 0; mt < 8; ++mt) {
      int rn = mt * 16 + lr;
      a[mt] = *(const short8*)(qb + rn * 512 + ((k0 * 2 + lk * 16) ^ ((rn & 7) << 4)));
    }
#pragma unroll
    for (int nt = 0; nt < 2; ++nt) {
      short8 bw = *(const short8*)(Mb + ((size_t)b << 16) + (size_t)(w * 32 + nt * 16 + lr) * 256 + k0 + lk * 8);
#pragma unroll
      for (int mt = 0; mt < 8; ++mt) acc[mt][nt] = mfma16(a[mt], bw, acc[mt][nt]);
    }
  }
  float* Yb = Y + (size_t)b * CC * NN;
#pragma unroll
  for (int mt = 0; mt < 8; ++mt)
#pragma unroll
    for (int nt = 0; nt < 2; ++nt) {
      int o = w * 32 + nt * 16 + lr;
      int nb = mt * 16 + 4 * lk;
      f32x4 out;
#pragma unroll
      for (int e = 0; e < 4; ++e) out[e] = acc[mt][nt][e] * recip_s[nb + e] + shift_s[o];
      *(f32x4*)(Yb + (size_t)o * NN + n0 + nb) = out;
    }
}

extern "C" void kernel_launch(void* const* d_in, const int* in_sizes, int n_in,
                              void* d_out, int out_size, void* d_ws, size_t ws_size,
                              hipStream_t stream) {
  const float* x = (const float*)d_in[0];
  const float* Wqkv = (const float*)d_in[1];
  const float* Wproj = (const float*)d_in[2];
  const float* g = (const float*)d_in[3];
  const float* bta = (const float*)d_in[4];
  const float* mu = (const float*)d_in[5];
  const float* var = (const float*)d_in[6];
  float* Y = (float*)d_out;

  char* ws = (char*)d_ws;
  size_t off = 0;
  auto alloc = [&](size_t bytes) -> void* {
    void* p = ws + off;
    off += (bytes + 255) & ~(size_t)255;
    return p;
  };
  const size_t big = (size_t)BB * NN * CC * 2;  // 33.5 MB
  bf16* KB = (bf16*)alloc(big);
  bf16* VB = (bf16*)alloc(big);
  float* PART = (float*)alloc((size_t)BB * 16 * 65536 * 4);  // 16.8 MB
  bf16* KVJ = (bf16*)alloc((size_t)BB * 65536 * 2);
  bf16* Mbuf = (bf16*)alloc((size_t)BB * 65536 * 2);
  float* KVD = (float*)alloc((size_t)BB * 256 * 4);
  bf16* Wq = (bf16*)alloc(256 * 256 * 2);
  bf16* Wkv = (bf16*)alloc(512 * 256 * 2);
  bf16* Wp = (bf16*)alloc(256 * 256 * 2);
  float* bns = (float*)alloc(512 * 4);

  prep_kernel<<<1025, 256, 0, stream>>>(Wqkv, Wproj, g, bta, mu, var, Wq, Wkv, Wp, bns, KVD);
  kv_kernel<<<dim3(NN / 128, BB), 512, 0, stream>>>(x, Wkv, KB, VB, KVD);
  g2_kernel<<<dim3(4, 16, BB), 256, 0, stream>>>(KB, VB, PART);
  kvred_kernel<<<BB * 65536 / 256, 256, 0, stream>>>(PART, KVJ);
  mker_kernel<<<dim3(2, 2, BB), 256, 0, stream>>>(Wp, KVJ, bns, Mbuf);
  g5_kernel<<<dim3(NN / 128, BB), 512, 0, stream>>>(x, Wq, Mbuf, KVD, bns, Y);
}

// Round 16
// 160.936 us; speedup vs baseline: 1.0868x; 1.0332x over previous
//
#include <hip/hip_runtime.h>
#include <hip/hip_bf16.h>

#define BB 4
#define CC 256
#define NN 16384

typedef __hip_bfloat16 bf16;
typedef __attribute__((ext_vector_type(8))) short short8;
typedef __attribute__((ext_vector_type(4))) short s16x4;
typedef __attribute__((ext_vector_type(4))) float f32x4;

__device__ __forceinline__ float b2f(unsigned short u) {
  union { unsigned int i; float f; } x; x.i = ((unsigned int)u) << 16; return x.f;
}
__device__ __forceinline__ short f2bs(float v) {
  bf16 h = __float2bfloat16(v);
  return *reinterpret_cast<short*>(&h);
}
__device__ __forceinline__ f32x4 mfma16(short8 a, short8 b, f32x4 c) {
  return __builtin_amdgcn_mfma_f32_16x16x32_bf16(a, b, c, 0, 0, 0);
}

// stage x[b, 0..255, n0..n0+127] f32 -> LDS xs[n][j] bf16, XOR-swizzled 16B chunks.
// 512 threads: n = t&127 (lane-coalesced), j-quarter = t>>7; 8 iters x 8 j each.
__device__ __forceinline__ void stage_x_T(const float* __restrict__ xsrc, char* xb_lds, int t) {
  int sn = t & 127;
  int jh = t >> 7;  // 0..3
#pragma unroll
  for (int i = 0; i < 8; ++i) {
    int j0 = (jh + 4 * i) * 8;
    float f[8];
#pragma unroll
    for (int jc = 0; jc < 8; ++jc) f[jc] = xsrc[(size_t)(j0 + jc) * NN + sn];
    short8 pk;
#pragma unroll
    for (int jc = 0; jc < 8; ++jc) pk[jc] = f2bs(f[jc]);
    *(short8*)(xb_lds + sn * 512 + ((j0 * 2) ^ ((sn & 7) << 4))) = pk;
  }
}

// ---------------- prep: reorder/convert weights, BN constants, zero KVD ----------------
__global__ __launch_bounds__(256) void prep_kernel(
    const float* __restrict__ Wqkv, const float* __restrict__ Wproj,
    const float* __restrict__ g, const float* __restrict__ bta,
    const float* __restrict__ mu, const float* __restrict__ var,
    bf16* __restrict__ Wq, bf16* __restrict__ Wkv, bf16* __restrict__ Wp,
    float* __restrict__ bns, float* __restrict__ KVD) {
  int i = blockIdx.x * 256 + threadIdx.x;
  if (i < 1024) KVD[i] = 0.f;
  if (i < 768 * 256) {
    int o = i >> 8, c8 = i & 255;
    int c = o / 3, s = o - 3 * c;
    bf16 bv = __float2bfloat16(Wqkv[i]);
    if (s == 0) Wq[c * 256 + c8] = bv;
    else if (s == 1) Wkv[c * 256 + c8] = bv;
    else Wkv[(256 + c) * 256 + c8] = bv;
  }
  int j = i - 768 * 256;
  if (j >= 0 && j < 256 * 256) Wp[j] = __float2bfloat16(Wproj[j]);
  int k = i - (768 * 256 + 256 * 256);
  if (k >= 0 && k < 256) {
    float sc = g[k] * rsqrtf(var[k] + 1e-5f);
    bns[k] = sc;
    bns[256 + k] = bta[k] - mu[k] * sc;
  }
}

// ---------------- kv: stage x; k phase + v phase; kvd folded ----------------
__global__ __launch_bounds__(512) void kv_kernel(
    const float* __restrict__ X, const bf16* __restrict__ Wkv,
    bf16* __restrict__ KB, bf16* __restrict__ VB, float* __restrict__ KVD) {
  __shared__ bf16 xs[128 * 256];  // 64 KB, rows 512B, 16B-chunk ^= (row&7)
  int b = blockIdx.y;
  int n0 = blockIdx.x * 128;
  int t = threadIdx.x, w = t >> 6, l = t & 63, lr = l & 15, lk = l >> 4;
  stage_x_T(X + (size_t)b * CC * NN + n0, (char*)xs, t);
  __syncthreads();
  const char* xb = (const char*)xs;
#pragma unroll
  for (int ph = 0; ph < 2; ++ph) {
    f32x4 acc[2][8] = {};
    for (int k0 = 0; k0 < 256; k0 += 32) {
      short8 a[2];
#pragma unroll
      for (int mt = 0; mt < 2; ++mt)
        a[mt] = *(const short8*)(Wkv + (size_t)(ph * 256 + w * 32 + mt * 16 + lr) * CC + k0 + lk * 8);
#pragma unroll
      for (int nt = 0; nt < 8; ++nt) {
        int rn = nt * 16 + lr;
        short8 bb = *(const short8*)(xb + rn * 512 + ((k0 * 2 + lk * 16) ^ ((rn & 7) << 4)));
#pragma unroll
        for (int mt = 0; mt < 2; ++mt) acc[mt][nt] = mfma16(a[mt], bb, acc[mt][nt]);
      }
    }
    bf16* Out = (ph == 0 ? KB : VB) + (size_t)b * CC * NN;
    if (ph == 0) {
#pragma unroll
      for (int mt = 0; mt < 2; ++mt)
#pragma unroll
        for (int e = 0; e < 4; ++e) {
          float s = 0.f;
#pragma unroll
          for (int nt = 0; nt < 8; ++nt) {
            float v = acc[mt][nt][e];
            v = v > 0.f ? v : 0.f;
            acc[mt][nt][e] = v;
            s += v;
          }
          s += __shfl_xor(s, 1);
          s += __shfl_xor(s, 2);
          s += __shfl_xor(s, 4);
          s += __shfl_xor(s, 8);
          int c = w * 32 + mt * 16 + 4 * lk + e;
          if (lr == 0) atomicAdd(&KVD[b * 256 + c], s);
        }
    }
#pragma unroll
    for (int mt = 0; mt < 2; ++mt)
#pragma unroll
      for (int nt = 0; nt < 8; ++nt)
#pragma unroll
        for (int e = 0; e < 4; ++e) {
          int c = w * 32 + mt * 16 + 4 * lk + e;
          int n = nt * 16 + lr;
          Out[(size_t)c * NN + n0 + n] = __float2bfloat16(acc[mt][nt][e]);
        }
  }
}

// ---------------- G2: PART[c][j] partials = k @ v^T, split-K 16 ----------------
__global__ __launch_bounds__(256) void g2_kernel(const bf16* __restrict__ KB,
                                                 const bf16* __restrict__ VB,
                                                 float* __restrict__ PART) {
  int b = blockIdx.z, chunk = blockIdx.y;
  int tc = (blockIdx.x & 1) * 128;
  int tj = (blockIdx.x >> 1) * 128;
  int nb = chunk * 1024;
  int t = threadIdx.x, w = t >> 6, lr = t & 15, lk = (t & 63) >> 4;
  const bf16* A = KB + ((size_t)b * CC + tc + w * 32) * NN + nb;
  const bf16* Bp = VB + ((size_t)b * CC + tj) * NN + nb;
  f32x4 acc[2][8] = {};
  for (int k0 = 0; k0 < 1024; k0 += 32) {
    short8 a[2];
#pragma unroll
    for (int mt = 0; mt < 2; ++mt)
      a[mt] = *(const short8*)(A + (size_t)(mt * 16 + lr) * NN + k0 + lk * 8);
#pragma unroll
    for (int nt = 0; nt < 8; ++nt) {
      short8 bb = *(const short8*)(Bp + (size_t)(nt * 16 + lr) * NN + k0 + lk * 8);
#pragma unroll
      for (int mt = 0; mt < 2; ++mt) acc[mt][nt] = mfma16(a[mt], bb, acc[mt][nt]);
    }
  }
  float* P = PART + (((size_t)(b * 16 + chunk)) << 16);
#pragma unroll
  for (int mt = 0; mt < 2; ++mt)
#pragma unroll
    for (int nt = 0; nt < 8; ++nt)
#pragma unroll
      for (int e = 0; e < 4; ++e) {
        int c = tc + w * 32 + mt * 16 + 4 * lk + e;
        int j = tj + nt * 16 + lr;
        P[(size_t)c * 256 + j] = acc[mt][nt][e];
      }
}

// ---------------- reduce partials -> KVJ bf16 [b][c][j] ----------------
__global__ __launch_bounds__(256) void kvred_kernel(const float* __restrict__ PART, bf16* __restrict__ KVJ) {
  int idx = blockIdx.x * 256 + threadIdx.x;
  int b = idx >> 16, rem = idx & 65535;
  float s = 0.f;
#pragma unroll
  for (int ch = 0; ch < 16; ++ch) s += PART[(((size_t)(b * 16 + ch)) << 16) + rem];
  KVJ[idx] = __float2bfloat16(s);
}

// ---------------- mker: M[o][c] = scale[o] * sum_j Wp[o,j] * KVJ[c,j] ----------------
__global__ __launch_bounds__(256) void mker_kernel(const bf16* __restrict__ Wp,
                                                   const bf16* __restrict__ KVJ,
                                                   const float* __restrict__ bns,
                                                   bf16* __restrict__ Mb) {
  int b = blockIdx.z;
  int o0 = blockIdx.x * 128, c0 = blockIdx.y * 128;
  int t = threadIdx.x, w = t >> 6, lr = t & 15, lk = (t & 63) >> 4;
  const bf16* A = Wp + (size_t)(o0 + w * 32) * 256;
  const bf16* Bp = KVJ + ((size_t)b << 16) + (size_t)c0 * 256;
  f32x4 acc[2][8] = {};
  for (int k0 = 0; k0 < 256; k0 += 32) {
    short8 a[2];
#pragma unroll
    for (int mt = 0; mt < 2; ++mt)
      a[mt] = *(const short8*)(A + (size_t)(mt * 16 + lr) * 256 + k0 + lk * 8);
#pragma unroll
    for (int nt = 0; nt < 8; ++nt) {
      short8 bb = *(const short8*)(Bp + (size_t)(nt * 16 + lr) * 256 + k0 + lk * 8);
#pragma unroll
      for (int mt = 0; mt < 2; ++mt) acc[mt][nt] = mfma16(a[mt], bb, acc[mt][nt]);
    }
  }
#pragma unroll
  for (int mt = 0; mt < 2; ++mt)
#pragma unroll
    for (int nt = 0; nt < 8; ++nt)
#pragma unroll
      for (int e = 0; e < 4; ++e) {
        int o = o0 + w * 32 + mt * 16 + 4 * lk + e;
        int c = c0 + nt * 16 + lr;
        Mb[((size_t)b << 16) + (size_t)o * 256 + c] = __float2bfloat16(acc[mt][nt][e] * bns[o]);
      }
}

// ---------------- g5: stage x, q in-kernel (b64 writeback), den, M-GEMM ----------------
__global__ __launch_bounds__(512) void g5_kernel(const float* __restrict__ X,
                                                 const bf16* __restrict__ Wq,
                                                 const bf16* __restrict__ Mb,
                                                 const float* __restrict__ KVD,
                                                 const float* __restrict__ bns,
                                                 float* __restrict__ Y) {
  __shared__ bf16 qs[128 * 256];
  __shared__ float recip_s[128];
  __shared__ float shift_s[256];
  int b = blockIdx.y;
  int n0 = blockIdx.x * 128;
  int t = threadIdx.x, w = t >> 6, l = t & 63, lr = l & 15, lk = l >> 4;
  if (t < 256) shift_s[t] = bns[256 + t];
  stage_x_T(X + (size_t)b * CC * NN + n0, (char*)qs, t);
  __syncthreads();
  char* qb = (char*)qs;
  {
    f32x4 qa[2][8] = {};
    for (int k0 = 0; k0 < 256; k0 += 32) {
      short8 a[2];
#pragma unroll
      for (int mt = 0; mt < 2; ++mt)
        a[mt] = *(const short8*)(Wq + (size_t)(w * 32 + mt * 16 + lr) * CC + k0 + lk * 8);
#pragma unroll
      for (int nt = 0; nt < 8; ++nt) {
        int rn = nt * 16 + lr;
        short8 bb = *(const short8*)(qb + rn * 512 + ((k0 * 2 + lk * 16) ^ ((rn & 7) << 4)));
#pragma unroll
        for (int mt = 0; mt < 2; ++mt) qa[mt][nt] = mfma16(a[mt], bb, qa[mt][nt]);
      }
    }
    __syncthreads();  // all waves done reading the x tile
#pragma unroll
    for (int mt = 0; mt < 2; ++mt)
#pragma unroll
      for (int nt = 0; nt < 8; ++nt) {
        int n = nt * 16 + lr;
        int c0 = w * 32 + mt * 16 + 4 * lk;
        s16x4 pk;
#pragma unroll
        for (int e = 0; e < 4; ++e) {
          float v = qa[mt][nt][e];
          pk[e] = f2bs(v > 0.f ? v : 0.f);
        }
        *(s16x4*)(qb + n * 512 + ((c0 * 2) ^ ((n & 7) << 4))) = pk;
      }
  }
  __syncthreads();
  {
    int row = t >> 2, qtr = t & 3;
    const float* kd = KVD + b * 256;
    float s = 0.f;
#pragma unroll
    for (int jj = 0; jj < 8; ++jj) {
      int chunk = qtr * 8 + jj;
      short8 v = *(const short8*)(qb + row * 512 + ((chunk * 16) ^ ((row & 7) << 4)));
      const float* kp = kd + chunk * 8;
#pragma unroll
      for (int e = 0; e < 8; ++e) s += b2f((unsigned short)v[e]) * kp[e];
    }
    s += __shfl_xor(s, 1);
    s += __shfl_xor(s, 2);
    if (qtr == 0) recip_s[row] = 1.f / (s + 1e-5f);
  }
  __syncthreads();
  f32x4 acc[8][2] = {};
  for (int k0 = 0; k0 < 256; k0 += 32) {
    short8 a[8];
#pragma unroll
    for (int mt = 0; mt < 8; ++mt) {
      int rn = mt * 16 + lr;
      a[mt] = *(const short8*)(qb + rn * 512 + ((k0 * 2 + lk * 16) ^ ((rn & 7) << 4)));
    }
#pragma unroll
    for (int nt = 0; nt < 2; ++nt) {
      short8 bw = *(const short8*)(Mb + ((size_t)b << 16) + (size_t)(w * 32 + nt * 16 + lr) * 256 + k0 + lk * 8);
#pragma unroll
      for (int mt = 0; mt < 8; ++mt) acc[mt][nt] = mfma16(a[mt], bw, acc[mt][nt]);
    }
  }
  float* Yb = Y + (size_t)b * CC * NN;
#pragma unroll
  for (int mt = 0; mt < 8; ++mt)
#pragma unroll
    for (int nt = 0; nt < 2; ++nt) {
      int o = w * 32 + nt * 16 + lr;
      int nb = mt * 16 + 4 * lk;
      f32x4 out;
#pragma unroll
      for (int e = 0; e < 4; ++e) out[e] = acc[mt][nt][e] * recip_s[nb + e] + shift_s[o];
      *(f32x4*)(Yb + (size_t)o * NN + n0 + nb) = out;
    }
}

extern "C" void kernel_launch(void* const* d_in, const int* in_sizes, int n_in,
                              void* d_out, int out_size, void* d_ws, size_t ws_size,
                              hipStream_t stream) {
  const float* x = (const float*)d_in[0];
  const float* Wqkv = (const float*)d_in[1];
  const float* Wproj = (const float*)d_in[2];
  const float* g = (const float*)d_in[3];
  const float* bta = (const float*)d_in[4];
  const float* mu = (const float*)d_in[5];
  const float* var = (const float*)d_in[6];
  float* Y = (float*)d_out;

  char* ws = (char*)d_ws;
  size_t off = 0;
  auto alloc = [&](size_t bytes) -> void* {
    void* p = ws + off;
    off += (bytes + 255) & ~(size_t)255;
    return p;
  };
  const size_t big = (size_t)BB * NN * CC * 2;  // 33.5 MB
  bf16* KB = (bf16*)alloc(big);
  bf16* VB = (bf16*)alloc(big);
  float* PART = (float*)alloc((size_t)BB * 16 * 65536 * 4);  // 16.8 MB
  bf16* KVJ = (bf16*)alloc((size_t)BB * 65536 * 2);
  bf16* Mbuf = (bf16*)alloc((size_t)BB * 65536 * 2);
  float* KVD = (float*)alloc((size_t)BB * 256 * 4);
  bf16* Wq = (bf16*)alloc(256 * 256 * 2);
  bf16* Wkv = (bf16*)alloc(512 * 256 * 2);
  bf16* Wp = (bf16*)alloc(256 * 256 * 2);
  float* bns = (float*)alloc(512 * 4);

  prep_kernel<<<1025, 256, 0, stream>>>(Wqkv, Wproj, g, bta, mu, var, Wq, Wkv, Wp, bns, KVD);
  kv_kernel<<<dim3(NN / 128, BB), 512, 0, stream>>>(x, Wkv, KB, VB, KVD);
  g2_kernel<<<dim3(4, 16, BB), 256, 0, stream>>>(KB, VB, PART);
  kvred_kernel<<<BB * 65536 / 256, 256, 0, stream>>>(PART, KVJ);
  mker_kernel<<<dim3(2, 2, BB), 256, 0, stream>>>(Wp, KVJ, bns, Mbuf);
  g5_kernel<<<dim3(NN / 128, BB), 512, 0, stream>>>(x, Wq, Mbuf, KVD, bns, Y);
}